// Round 1
// 137.029 us; speedup vs baseline: 1.0199x; 1.0199x over previous
//
#include <hip/hip_runtime.h>
#include <hip/hip_fp16.h>
#include <cmath>

#define NLOD 10

// ---------------------------------------------------------------------------
// LDS layout (all compile-time):
//   [hashed levels 4..9]  4825 entries   bytes      0 .. 38600
//   [dense grids 0..3]    4930 vertices  bytes  38600 .. 78040
// Hashed levels come FIRST so every ds_read offset immediate (level base +
// corner delta) stays < 65536.  78040 B/block -> two 1024-thread blocks/CU
// (156 KB of 160 KB), full 2048-thread occupancy retained.
//
// Levels 0..3 are staged DE-HASHED: the per-vertex hash+mod is computed once
// per block at staging (4930 vertices), and the hot loop addresses them by
// linear vertex coordinate -> no hash, no magic-modulo, no per-corner
// address math (corner deltas fold into ds_read offset immediates).
// res = {7,8,11,14} for these levels is numerically robust (6*b^l is far
// from integer boundaries for l=0..3; only LOD 9 is boundary-sensitive).
// ---------------------------------------------------------------------------
static constexpr int HSIZES[6] = {324, 529, 900, 1024, 1024, 1024}; // levels 4..9
static constexpr int HENT[6]   = {0, 324, 853, 1753, 2777, 3801};   // entry offsets
static constexpr int DENSE_BASE_ENT = 4825;                          // after hashed
// dense grids: res 7,8,11,14 -> cubes 343,512,1331,2744
static constexpr int DENT[4]   = {4825, 5168, 5680, 7011};           // entry offsets
static constexpr int TOTAL_ENTRIES = 9755;                           // 4825 + 4930
// LDS bytes = 9755 * 8 = 78040

struct ResArr { int r[NLOD]; };

// One ds_read_b64 per corner; three v_fma_mix_f32 consume the f16 halves in
// place via op_sel (numerically identical to fpext+fma, both exact/fused).
__device__ __forceinline__ void fmix_accum(uint2 raw, float wt,
                                           float& a0, float& a1, float& a2)
{
    asm("v_fma_mix_f32 %0, %1, %2, %0 op_sel_hi:[1,0,0]"
        : "+v"(a0) : "v"(raw.x), "v"(wt));
    asm("v_fma_mix_f32 %0, %1, %2, %0 op_sel:[1,0,0] op_sel_hi:[1,0,0]"
        : "+v"(a1) : "v"(raw.x), "v"(wt));
    asm("v_fma_mix_f32 %0, %1, %2, %0 op_sel_hi:[1,0,0]"
        : "+v"(a2) : "v"(raw.y), "v"(wt));
}

// ---------------------------------------------------------------------------
// Dense (de-hashed) levels 0..3.  LBASE = byte offset of this level's grid.
// Address math is 3 float ops + 1 cvt: lin = ((gx*RES+gy)*RES+gz)*8 is an
// exact integer-valued float (all terms < 2^24), corner deltas are constant
// immediates on the ds_read.
// ---------------------------------------------------------------------------
template <int RES, int LBASE>
__device__ __forceinline__ void dense_accum(const char* lds,
                                            float px, float py, float pz,
                                            float& a0, float& a1, float& a2)
{
    constexpr float S = (float)(RES - 1);
    float fx = px * S, fy = py * S, fz = pz * S;

    // clip(floor(x),0,res-2) == floor(x) here, exactly (same proof as the
    // hashed path: px in [0,1), res-1 in [6,64]).
    float gx = floorf(fx), gy = floorf(fy), gz = floorf(fz);
    float wx = fx - gx, wy = fy - gy, wz = fz - gz;

    float lin = fmaf(gx, (float)(RES * RES * 8),
                 fmaf(gy, (float)(RES * 8), gz * 8.0f));
    unsigned base = (unsigned)lin;   // exact: lin is a non-negative integer

    float wx0 = 1.0f - wx, wy0 = 1.0f - wy, wz0 = 1.0f - wz;
    float w00 = wx0 * wy0, w01 = wx0 * wy, w10 = wx * wy0, w11 = wx * wy;

#define DCORNER(I, J, K, WT)                                                   \
    fmix_accum(*reinterpret_cast<const uint2*>(                                \
                   lds + base + (LBASE + ((I)*RES*RES + (J)*RES + (K)) * 8)),  \
               (WT), a0, a1, a2);

    // reference OFFSETS order: (i,j,k) for i in(0,1) j in(0,1) k in(0,1)
    DCORNER(0, 0, 0, w00 * wz0)
    DCORNER(0, 0, 1, w00 * wz)
    DCORNER(0, 1, 0, w01 * wz0)
    DCORNER(0, 1, 1, w01 * wz)
    DCORNER(1, 0, 0, w10 * wz0)
    DCORNER(1, 0, 1, w10 * wz)
    DCORNER(1, 1, 0, w11 * wz0)
    DCORNER(1, 1, 1, w11 * wz)
#undef DCORNER
}

// ---------------------------------------------------------------------------
// Hashed levels 4..9 (unchanged math from the previous kernel).
// ---------------------------------------------------------------------------
template <int SIZE>
__device__ __forceinline__ void level_accum(const __half* __restrict__ cb, int res,
                                            float px, float py, float pz,
                                            float& a0, float& a1, float& a2)
{
    constexpr bool POW2 = (SIZE & (SIZE - 1)) == 0;
    constexpr unsigned P1 = 2654435761u, P2 = 805459861u;

    const float s = (float)(res - 1);
    float fx = px * s, fy = py * s, fz = pz * s;

    float gx = floorf(fx), gy = floorf(fy), gz = floorf(fz);
    float wx = fx - gx, wy = fy - gy, wz = fz - gz;

    unsigned ux = (unsigned)(int)gx;
    unsigned uy = (unsigned)(int)gy;
    unsigned uz = (unsigned)(int)gz;

    // Incremental hash terms: h = (x*1) ^ (y*P1) ^ (z*P2).
    // For pow2 SIZE fold the *8 byte-scale into the components.
    unsigned hx0, hx1, hy0, hy1, hz0, hz1;
    if constexpr (POW2) {
        hx0 = ux << 3;        hx1 = hx0 + 8u;
        hy0 = uy * (P1 * 8u); hy1 = hy0 + (P1 * 8u);
        hz0 = uz * (P2 * 8u); hz1 = hz0 + (P2 * 8u);
    } else {
        hx0 = ux;       hx1 = ux + 1u;
        hy0 = uy * P1;  hy1 = hy0 + P1;
        hz0 = uz * P2;  hz1 = hz0 + P2;
    }
    unsigned h00 = hx0 ^ hy0, h01 = hx0 ^ hy1;
    unsigned h10 = hx1 ^ hy0, h11 = hx1 ^ hy1;

    float wx0 = 1.0f - wx, wy0 = 1.0f - wy, wz0 = 1.0f - wz;
    float w00 = wx0 * wy0, w01 = wx0 * wy, w10 = wx * wy0, w11 = wx * wy;

    auto corner = [&](unsigned h, float wt) {
        uint2 raw;
        if constexpr (POW2) {
            unsigned addr = h & (unsigned)((SIZE - 1) * 8);
            raw = *reinterpret_cast<const uint2*>(
                      reinterpret_cast<const char*>(cb) + addr);
        } else {
            unsigned idx = h % (unsigned)SIZE;   // constexpr divisor -> magic mul
            raw = reinterpret_cast<const uint2*>(cb)[idx];
        }
        fmix_accum(raw, wt, a0, a1, a2);
    };

    corner(h00 ^ hz0, w00 * wz0);
    corner(h00 ^ hz1, w00 * wz);
    corner(h01 ^ hz0, w01 * wz0);
    corner(h01 ^ hz1, w01 * wz);
    corner(h10 ^ hz0, w10 * wz0);
    corner(h10 ^ hz1, w10 * wz);
    corner(h11 ^ hz0, w11 * wz0);
    corner(h11 ^ hz1, w11 * wz);
}

// Stage one dense de-hashed grid: per vertex (x,y,z), compute the Instant-NGP
// hash once, gather the codebook entry, compress to f16, store at the linear
// vertex index.  ~5 vertices/thread for 1024-thread blocks.
template <int RES, int SIZE, int ENT>
__device__ __forceinline__ void stage_dense(const float* __restrict__ src,
                                            __half* cbh)
{
    constexpr unsigned P1 = 2654435761u, P2 = 805459861u;
    for (int v = threadIdx.x; v < RES * RES * RES; v += 1024) {
        int z = v % RES;
        int t = v / RES;
        int y = t % RES;
        int x = t / RES;
        unsigned h = (unsigned)x ^ ((unsigned)y * P1) ^ ((unsigned)z * P2);
        unsigned idx = h % (unsigned)SIZE;        // constexpr divisor
        const float* s = src + idx * 3;
        __half2* d = reinterpret_cast<__half2*>(cbh + (ENT + v) * 4);
        d[0] = __floats2half2_rn(s[0], s[1]);
        d[1] = __floats2half2_rn(s[2], 0.0f);
    }
}

__global__ __launch_bounds__(1024, 8)
void hashgrid_kernel(const float* __restrict__ pts,
                     const float* __restrict__ c0, const float* __restrict__ c1,
                     const float* __restrict__ c2, const float* __restrict__ c3,
                     const float* __restrict__ c4, const float* __restrict__ c5,
                     const float* __restrict__ c6, const float* __restrict__ c7,
                     const float* __restrict__ c8, const float* __restrict__ c9,
                     float* __restrict__ out, int npts, ResArr res)
{
    __shared__ __half cbh[TOTAL_ENTRIES * 4];   // 78040 B
    const char* lds = reinterpret_cast<const char*>(cbh);

    // ---- stage hashed levels 4..9 (copy + compress) ----
    {
        const float* hs[6] = {c4, c5, c6, c7, c8, c9};
#pragma unroll
        for (int L = 0; L < 6; ++L) {
            for (int e = threadIdx.x; e < HSIZES[L]; e += 1024) {
                const float* s = hs[L] + e * 3;
                __half2* d = reinterpret_cast<__half2*>(cbh + (HENT[L] + e) * 4);
                d[0] = __floats2half2_rn(s[0], s[1]);
                d[1] = __floats2half2_rn(s[2], 0.0f);
            }
        }
    }
    // ---- stage dense de-hashed grids, levels 0..3 ----
    stage_dense< 7,  49, 4825>(c0, cbh);
    stage_dense< 8,  64, 5168>(c1, cbh);
    stage_dense<11, 121, 5680>(c2, cbh);
    stage_dense<14, 196, 7011>(c3, cbh);
    __syncthreads();

    // Two points per thread per iteration: 16 independent gathers in flight
    // per wave, doubling latency hiding.  512 blk x 1024 thr, S = 524288,
    // npts = 2M -> exactly 2 loop iterations for every thread.
    const int S = gridDim.x * blockDim.x;
    for (int n = blockIdx.x * blockDim.x + threadIdx.x; n < npts; n += 2 * S) {
        const int m = n + S;
        const bool hasB = (m < npts);
        const int mc = hasB ? m : n;      // clamp: B duplicates A, store suppressed

        float ax = pts[n * 3 + 0], ay = pts[n * 3 + 1], az = pts[n * 3 + 2];
        float bx = pts[mc * 3 + 0], by = pts[mc * 3 + 1], bz = pts[mc * 3 + 2];

        float A0 = 0.0f, A1 = 0.0f, A2 = 0.0f;
        float B0 = 0.0f, B1 = 0.0f, B2 = 0.0f;

        // levels 0..3: dense de-hashed grids (no hash, no modulo, corner
        // deltas are ds_read offset immediates)
#define DLEVEL2(RES, ENT)                                       \
        dense_accum<RES, (ENT) * 8>(lds, ax, ay, az, A0, A1, A2); \
        dense_accum<RES, (ENT) * 8>(lds, bx, by, bz, B0, B1, B2);

        DLEVEL2( 7, 4825)
        DLEVEL2( 8, 5168)
        DLEVEL2(11, 5680)
        DLEVEL2(14, 7011)
#undef DLEVEL2

        // levels 4..9: hashed lookups (magic-mod for 324/529/900, masked pow2
        // for the 1024s)
#define HLEVEL2(SZ, HL)                                                               \
        level_accum<SZ>(cbh + HENT[HL] * 4, res.r[(HL) + 4], ax, ay, az, A0, A1, A2); \
        level_accum<SZ>(cbh + HENT[HL] * 4, res.r[(HL) + 4], bx, by, bz, B0, B1, B2);

        HLEVEL2( 324, 0)
        HLEVEL2( 529, 1)
        HLEVEL2( 900, 2)
        HLEVEL2(1024, 3)
        HLEVEL2(1024, 4)
        HLEVEL2(1024, 5)
#undef HLEVEL2

        out[n * 3 + 0] = A0;
        out[n * 3 + 1] = A1;
        out[n * 3 + 2] = A2;
        if (hasB) {
            out[m * 3 + 0] = B0;
            out[m * 3 + 1] = B1;
            out[m * 3 + 2] = B2;
        }
    }
}

extern "C" void kernel_launch(void* const* d_in, const int* in_sizes, int n_in,
                              void* d_out, int out_size, void* d_ws, size_t ws_size,
                              hipStream_t stream)
{
    const float* pts = (const float*)d_in[0];
    const int npts = in_sizes[0] / 3;

    // Replicate numpy's exact double-precision LOD computation (glibc libm):
    // LOD 9 sits at 6*b^9 == 64.0 +/- ~1e-14, floor() is boundary-sensitive.
    // (Only levels 4..9 are consumed at runtime; 0..3 are compile-time dense.)
    ResArr ra;
    const double b = exp((log(64.0) - log(6.0)) / 9.0);
    for (int l = 0; l < NLOD; ++l)
        ra.r[l] = (int)(1.0 + floor(6.0 * pow(b, (double)l)));

    // 512 blocks x 1024 thr: 2 blocks/CU (156 KB LDS), 32 waves/CU.
    hashgrid_kernel<<<dim3(512), dim3(1024), 0, stream>>>(
        pts,
        (const float*)d_in[1], (const float*)d_in[2], (const float*)d_in[3],
        (const float*)d_in[4], (const float*)d_in[5], (const float*)d_in[6],
        (const float*)d_in[7], (const float*)d_in[8], (const float*)d_in[9],
        (const float*)d_in[10],
        (float*)d_out, npts, ra);
}